// Round 8
// baseline (696.820 us; speedup 1.0000x reference)
//
#include <hip/hip_runtime.h>
#include <hip/hip_bf16.h>
#include <cstdint>
#include <cstddef>

typedef __hip_bfloat16 bf16;
using short8 = __attribute__((ext_vector_type(8))) short;
using f32x4  = __attribute__((ext_vector_type(4))) float;
using float4v = __attribute__((ext_vector_type(4))) float;
using uint4v  = __attribute__((ext_vector_type(4))) unsigned int;

__device__ __forceinline__ float s2f(short s) {
  unsigned u = ((unsigned)(unsigned short)s) << 16;
  return __builtin_bit_cast(float, u);
}
__device__ __forceinline__ short f2s(float f) {  // RNE f32->bf16
  unsigned u = __builtin_bit_cast(unsigned, f);
  u += 0x7fffu + ((u >> 16) & 1u);
  return (short)(u >> 16);
}
__device__ __forceinline__ float bclo(unsigned u) { return __builtin_bit_cast(float, u << 16); }
__device__ __forceinline__ float bchi(unsigned u) { return __builtin_bit_cast(float, u & 0xFFFF0000u); }

__device__ __forceinline__ void gl_lds16(const void* g, void* l) {
  __builtin_amdgcn_global_load_lds((const __attribute__((address_space(1))) void*)g,
                                   (__attribute__((address_space(3))) void*)l, 16, 0, 0);
}

// ---------------- merged 1x1 conv + PReLU into zero-padded (+1 ring) f32 outputs ----
__global__ __launch_bounds__(256) void k_conv_all(
    const float* __restrict__ in_l, const float* __restrict__ in_s,
    const float* __restrict__ w_mlb, const float* __restrict__ b_mlb, const float* __restrict__ a_mlb,
    const float* __restrict__ w_m,   const float* __restrict__ b_m,   const float* __restrict__ a_m,
    const float* __restrict__ w_asm, const float* __restrict__ b_asm, const float* __restrict__ a_asm,
    float* __restrict__ MBpad, float* __restrict__ REFpad, float* __restrict__ BASEpad,
    int t1, int t2, int t3)
{
  int idx = blockIdx.x * 256 + threadIdx.x;
  const float *in, *w, *bi, *ap; float* o; int Cout, Hin, Win;
  if (idx < t1) { in = in_l; w = w_mlb; bi = b_mlb; ap = a_mlb; o = MBpad; Cout = 32; Hin = 96; Win = 96; }
  else if (idx < t1 + t2) { idx -= t1; in = in_s; w = w_m; bi = b_m; ap = a_m; o = REFpad; Cout = 32; Hin = 48; Win = 48; }
  else if (idx < t1 + t2 + t3) { idx -= t1 + t2; in = in_s; w = w_asm; bi = b_asm; ap = a_asm; o = BASEpad; Cout = 64; Hin = 48; Win = 48; }
  else return;
  int Wp = Win + 2, Hp = Hin + 2;
  int x = idx % Wp;
  int t = idx / Wp;
  int y = t % Hp; t /= Hp;
  int oc = t % Cout; int n = t / Cout;
  if (x == 0 || x == Wp - 1 || y == 0 || y == Hp - 1) { o[idx] = 0.0f; return; }
  int cs = Hin * Win;
  const float* ip = in + (size_t)n * 64 * cs + (size_t)(y - 1) * Win + (x - 1);
  const float* wp = w + oc * 64;
  float s = bi[oc];
#pragma unroll 16
  for (int ci = 0; ci < 64; ci++)
    s += wp[ci] * ip[(size_t)ci * cs];
  float a = ap[0];
  o[idx] = s >= 0.0f ? s : a * s;
}

// ---------------- merged gather/pack: Kp (stride 320) + Xp (stride 320) + Bb --------
__global__ __launch_bounds__(256) void k_gather_all(
    const float* __restrict__ mbpad, const float* __restrict__ refpad,
    const float* __restrict__ basepad,
    bf16* __restrict__ Kp, bf16* __restrict__ Xp, bf16* __restrict__ Bb)
{
  int b = blockIdx.x;
  int tid = threadIdx.x;
  if (b < 2304) {
    int wid = b * 4 + (tid >> 6);
    int lane = tid & 63;
    int n = wid / 2304, l = wid % 2304, lh = l / 48, lw = l % 48;
    float v[5]; float ss = 0.f;
#pragma unroll
    for (int i = 0; i < 5; i++) {
      int k = lane + 64 * i; v[i] = 0.f;
      if (k < 288) {
        int c = k / 9, rr = (k % 9) / 3, sc = k % 3;
        v[i] = refpad[((size_t)(n * 32 + c) * 50 + lh + rr) * 50 + lw + sc];
        ss += v[i] * v[i];
      }
    }
#pragma unroll
    for (int off = 32; off; off >>= 1) ss += __shfl_xor(ss, off);
    float inv = 10.f / (sqrtf(ss) + 1e-4f);
#pragma unroll
    for (int i = 0; i < 5; i++) {
      int k = lane + 64 * i;
      Kp[(size_t)wid * 320 + k] = __float2bfloat16(k < 288 ? v[i] * inv : 0.f);
    }
  } else if (b < 2304 + 46080) {
    int idx = (b - 2304) * 256 + tid;
    int k = idx % 320; int p = (idx / 320) % 9216; int n = idx / (320 * 9216);
    float val = 0.f;
    if (k < 288) {
      int c = k / 9, rr = (k % 9) / 3, sc = k % 3;
      int ph = p / 96, pw = p % 96;
      val = mbpad[((size_t)(n * 32 + c) * 98 + ph + rr) * 98 + pw + sc];
    }
    Xp[idx] = __float2bfloat16(val);
  } else {
    int idx = (b - 48384) * 256 + tid;
    int l = idx % 2304; int o = (idx / 2304) % 64; int n = idx / (2304 * 64);
    int lh = l / 48, lw = l % 48;
    Bb[idx] = __float2bfloat16(basepad[((size_t)(n * 64 + o) * 50 + lh + 1) * 50 + lw + 1]);
  }
}

// ---------------- stage 1: QK tile GEMM + chunk-local softmax, writes P~ ------------
// block: 64q x 256l, 2x2 waves of 32q x 128l. Ks staged via global_load_lds (DMA,
// width 16) into unpadded 256x64 LDS with source-side XOR swizzle: row R's col j
// lives at slot j^(R&7) -> frag ds_read_b128 lands 2-way (free), staging is
// lane-contiguous as the DMA requires.
__global__ __launch_bounds__(256, 4) void k_qk(
    const bf16* __restrict__ Xp, const bf16* __restrict__ Kp,
    bf16* __restrict__ attnT, float* __restrict__ statsM, float* __restrict__ statsZ,
    int n, int qlo)
{
  __shared__ __align__(16) short KsPs[16896];   // union: Ks 256x64 / Ps 64x264
  __shared__ float Sm[2][2][32];
  __shared__ float Sz[2][2][32];
  int tid = threadIdx.x, lane = tid & 63, wv = tid >> 6;
  int quad = lane >> 4, m16 = lane & 15;
  int wr = wv >> 1, wc = wv & 1;
  int q0 = qlo + blockIdx.x * 64;
  int l0 = blockIdx.y * 256;

  f32x4 acc[2][8];
#pragma unroll
  for (int mi = 0; mi < 2; mi++)
#pragma unroll
    for (int t = 0; t < 8; t++) acc[mi][t] = (f32x4){0.f, 0.f, 0.f, 0.f};

  const short* Xrow = (const short*)Xp + ((size_t)n * 9216 + q0 + wr * 32 + m16) * 320;
  const short* Ksrc = (const short*)Kp + ((size_t)n * 2304 + l0) * 320;
  int lrow = lane >> 3;              // 0..7 within wave-call
  int cslot = lane & 7;
  int csrc8 = (cslot ^ lrow) * 8;    // (R&7) == lrow since bases are mult of 8

#pragma unroll
  for (int s = 0; s < 5; s++) {
    __syncthreads();
#pragma unroll
    for (int p = 0; p < 8; p++) {
      int rbase = p * 32 + wv * 8;
      const short* g = &Ksrc[(size_t)(rbase + lrow) * 320 + s * 64 + csrc8];
      gl_lds16(g, &KsPs[rbase * 64]);
    }
    __syncthreads();
#pragma unroll
    for (int half = 0; half < 2; half++) {
      int kc = s * 64 + half * 32;
      if (kc >= 288) break;       // K=288; skip zero tail
      short8 a0 = *(const short8*)&Xrow[kc + quad * 8];
      short8 a1 = *(const short8*)&Xrow[16 * 320 + kc + quad * 8];
      int j = half * 4 + quad;
#pragma unroll
      for (int t = 0; t < 8; t++) {
        int R = wc * 128 + t * 16 + m16;
        short8 bfr = *(const short8*)&KsPs[R * 64 + ((j ^ (R & 7)) * 8)];
        acc[0][t] = __builtin_amdgcn_mfma_f32_16x16x32_bf16(a0, bfr, acc[0][t], 0, 0, 0);
        acc[1][t] = __builtin_amdgcn_mfma_f32_16x16x32_bf16(a1, bfr, acc[1][t], 0, 0, 0);
      }
    }
  }

  // local stats over this wave's 128 l
  float mloc[2][4], zloc[2][4], scale[2][4];
#pragma unroll
  for (int mi = 0; mi < 2; mi++)
#pragma unroll
    for (int r = 0; r < 4; r++) mloc[mi][r] = -3.0e38f;
#pragma unroll
  for (int mi = 0; mi < 2; mi++)
#pragma unroll
    for (int t = 0; t < 8; t++)
#pragma unroll
      for (int r = 0; r < 4; r++) mloc[mi][r] = fmaxf(mloc[mi][r], acc[mi][t][r]);
#pragma unroll
  for (int off = 1; off < 16; off <<= 1)
#pragma unroll
    for (int mi = 0; mi < 2; mi++)
#pragma unroll
      for (int r = 0; r < 4; r++) mloc[mi][r] = fmaxf(mloc[mi][r], __shfl_xor(mloc[mi][r], off));
#pragma unroll
  for (int mi = 0; mi < 2; mi++)
#pragma unroll
    for (int r = 0; r < 4; r++) zloc[mi][r] = 0.f;
#pragma unroll
  for (int mi = 0; mi < 2; mi++)
#pragma unroll
    for (int t = 0; t < 8; t++)
#pragma unroll
      for (int r = 0; r < 4; r++) {
        float e = __expf(acc[mi][t][r] - mloc[mi][r]);
        acc[mi][t][r] = e;
        zloc[mi][r] += e;
      }
#pragma unroll
  for (int off = 1; off < 16; off <<= 1)
#pragma unroll
    for (int mi = 0; mi < 2; mi++)
#pragma unroll
      for (int r = 0; r < 4; r++) zloc[mi][r] += __shfl_xor(zloc[mi][r], off);
  if (m16 == 0) {
#pragma unroll
    for (int mi = 0; mi < 2; mi++)
#pragma unroll
      for (int r = 0; r < 4; r++) {
        int qi = mi * 16 + quad * 4 + r;
        Sm[wc][wr][qi] = mloc[mi][r];
        Sz[wc][wr][qi] = zloc[mi][r];
      }
  }
  __syncthreads();   // stats visible; also guards Ks reuse as Ps below
#pragma unroll
  for (int mi = 0; mi < 2; mi++)
#pragma unroll
    for (int r = 0; r < 4; r++) {
      int qi = mi * 16 + quad * 4 + r;
      float mo = Sm[wc ^ 1][wr][qi];
      float zo = Sz[wc ^ 1][wr][qi];
      float mc = fmaxf(mloc[mi][r], mo);
      float sc = __expf(mloc[mi][r] - mc);
      scale[mi][r] = sc;
      if (m16 == 0 && wc == 0) {
        float zc = zloc[mi][r] * sc + zo * __expf(mo - mc);
        int qq = q0 + wr * 32 + qi;
        statsM[blockIdx.y * 9216 + qq] = mc;
        statsZ[blockIdx.y * 9216 + qq] = zc;
      }
    }
  // write P~ tile through LDS (coalesced global stores)
#pragma unroll
  for (int mi = 0; mi < 2; mi++)
#pragma unroll
    for (int t = 0; t < 8; t++)
#pragma unroll
      for (int r = 0; r < 4; r++)
        KsPs[(wr * 32 + mi * 16 + quad * 4 + r) * 264 + wc * 128 + t * 16 + m16] =
            f2s(acc[mi][t][r] * scale[mi][r]);
  __syncthreads();
  {
    int row = tid >> 2, part = tid & 3;
    short* dst = (short*)attnT + (size_t)(q0 - qlo + row) * 2304 + l0 + part * 64;
    const short* sp = &KsPs[row * 264 + part * 64];
#pragma unroll
    for (int v = 0; v < 8; v++)
      *(short8*)&dst[v * 8] = *(const short8*)&sp[v * 8];
  }
}

// ---------------- stage 2: combine chunk stats -> alpha[c][q] ----------------
__global__ __launch_bounds__(256) void k_alpha(
    const float* __restrict__ statsM, const float* __restrict__ statsZ,
    float* __restrict__ alpha, int qlo, int qlen)
{
  int i = blockIdx.x * 256 + threadIdx.x;
  if (i >= qlen) return;
  int q = qlo + i;
  float M = -3.0e38f;
#pragma unroll
  for (int c = 0; c < 9; c++) M = fmaxf(M, statsM[c * 9216 + q]);
  float Z = 0.f;
#pragma unroll
  for (int c = 0; c < 9; c++) Z += statsZ[c * 9216 + q] * __expf(statsM[c * 9216 + q] - M);
  float invZ = 1.f / Z;
#pragma unroll
  for (int c = 0; c < 9; c++) alpha[c * 9216 + q] = __expf(statsM[c * 9216 + q] - M) * invZ;
}

// ---- stage 3+4 fused: stencil -> LDS A2 tile -> split-K PV GEMM ------------------
// block = 16q x 64o. Phase 1: 256 threads compute A2[16][2304] (9-pt diagonal
// stencil with fused alpha, validated k_a2 code) into per-wave LDS chunks.
// Phase 2: wave wv owns k in [wv*576,(wv+1)*576): A-frags from LDS, B from global
// (L2-resident Bb), no barriers in k-loop; LDS reduction + fused epilogue.
__global__ __launch_bounds__(256, 2) void k_pv4(
    const bf16* __restrict__ attnT, const float* __restrict__ alpha,
    const bf16* __restrict__ Bb, const float* __restrict__ inl,
    float* __restrict__ out, int n, int bandq0, int qlo)
{
  __shared__ __align__(16) short A2s[4][16][580];   // 74.2 KB; tail reused for Cred
  int tid = threadIdx.x, lane = tid & 63, wv = tid >> 6;
  int quad = lane >> 4, m16 = lane & 15;
  int bpx = gridDim.x >> 3;
  int bx = blockIdx.x;
  int nb = (bx & 7) * bpx + (bx >> 3);   // XCD-contiguous q bands
  int q0 = bandq0 + nb * 16;

  // ---- phase 1: stencil ----
#pragma unroll
  for (int i = 0; i < 9; i++) {
    int G = tid + 256 * i;              // 0..2303 = 16 q-rows x 144 groups of 16 l
    int qrel = G / 144, j = G - qrel * 144;
    int l0 = j * 16;
    int q = q0 + qrel;
    int h = q / 96, w = q - h * 96;
    int lh = l0 / 48, lw0 = l0 - lh * 48;
    const short* att = (const short*)attnT;
    float acc[16];
#pragma unroll
    for (int k = 0; k < 16; k++) acc[k] = 0.f;
#pragma unroll
    for (int di = -1; di <= 1; di++) {
      int hh = h + di, lhh = lh + di;
      if (hh < 0 || hh >= 96 || lhh < 0 || lhh >= 48) continue;
      int lb = l0 + 48 * di;
      int qv = q + 96 * di;
      const short* r0 = att + (size_t)(qv - qlo) * 2304;
      int c0 = lb >> 8;
      const float* alc = alpha + c0 * 9216;
      { // dj = 0
        float a = alc[qv];
        uint4v Va = *(const uint4v*)(r0 + lb);
        uint4v Vb = *(const uint4v*)(r0 + lb + 8);
#pragma unroll
        for (int k = 0; k < 4; k++) {
          acc[2 * k]      += bclo(Va[k]) * a;  acc[2 * k + 1]  += bchi(Va[k]) * a;
          acc[8 + 2 * k]  += bclo(Vb[k]) * a;  acc[9 + 2 * k]  += bchi(Vb[k]) * a;
        }
      }
      if (w > 0) { // dj = -1
        const short* rm = r0 - 2304;
        int qp = qv - 1;
        float am = alc[qp];
        float a0 = ((lb & 255) == 0 && c0 > 0) ? alpha[(c0 - 1) * 9216 + qp] : am;
        uint4v Ma = *(const uint4v*)(rm + lb);
        uint4v Mb = *(const uint4v*)(rm + lb + 8);
        unsigned P = *(const unsigned*)(rm + lb - 2);
        unsigned D[8] = { Ma[0], Ma[1], Ma[2], Ma[3], Mb[0], Mb[1], Mb[2], Mb[3] };
        unsigned E0 = (P >> 16) | (D[0] << 16);
        if (lw0 == 0) E0 &= 0xFFFF0000u;
        acc[0] += bclo(E0) * a0;  acc[1] += bchi(E0) * am;
#pragma unroll
        for (int k = 1; k < 8; k++) {
          unsigned Ek = (D[k - 1] >> 16) | (D[k] << 16);
          acc[2 * k] += bclo(Ek) * am;  acc[2 * k + 1] += bchi(Ek) * am;
        }
      }
      if (w < 95) { // dj = +1
        const short* rp = r0 + 2304;
        int qp = qv + 1;
        float am = alc[qp];
        float a15 = ((lb & 255) == 240 && c0 < 8) ? alpha[(c0 + 1) * 9216 + qp] : am;
        uint4v Pa = *(const uint4v*)(rp + lb);
        uint4v Pb = *(const uint4v*)(rp + lb + 8);
        unsigned N = *(const unsigned*)(rp + lb + 16);
        unsigned D[9] = { Pa[0], Pa[1], Pa[2], Pa[3], Pb[0], Pb[1], Pb[2], Pb[3], N };
        unsigned F7 = (D[7] >> 16) | (D[8] << 16);
        if (lw0 == 32) F7 &= 0x0000FFFFu;
#pragma unroll
        for (int k = 0; k < 7; k++) {
          unsigned Fk = (D[k] >> 16) | (D[k + 1] << 16);
          acc[2 * k] += bclo(Fk) * am;  acc[2 * k + 1] += bchi(Fk) * am;
        }
        acc[14] += bclo(F7) * am;  acc[15] += bchi(F7) * a15;
      }
    }
    short8 o0, o1;
#pragma unroll
    for (int k = 0; k < 8; k++) { o0[k] = f2s(acc[k]); o1[k] = f2s(acc[8 + k]); }
    int w4 = l0 / 576, ll = l0 - w4 * 576;
    short* dst = &A2s[w4][qrel][ll];
    *(short8*)dst = o0;
    *(short8*)(dst + 8) = o1;
  }
  __syncthreads();

  // ---- phase 2: split-K GEMM ----
  f32x4 acc4[4];
#pragma unroll
  for (int t = 0; t < 4; t++) acc4[t] = (f32x4){0.f, 0.f, 0.f, 0.f};
  const short* Bp = (const short*)Bb + (size_t)n * 64 * 2304 + wv * 576;
#pragma unroll
  for (int it = 0; it < 9; it++) {
    int kw = it * 64;
#pragma unroll
    for (int ks = 0; ks < 64; ks += 32) {
      short8 a = *(const short8*)&A2s[wv][m16][kw + ks + quad * 8];
#pragma unroll
      for (int ni = 0; ni < 4; ni++) {
        short8 b = *(const short8*)&Bp[(size_t)(ni * 16 + m16) * 2304 + kw + ks + quad * 8];
        acc4[ni] = __builtin_amdgcn_mfma_f32_16x16x32_bf16(a, b, acc4[ni], 0, 0, 0);
      }
    }
  }
  __syncthreads();   // done reading A2s; reuse as Cred
  float* Cred = (float*)&A2s[0][0][0];   // [4][16][67]
#pragma unroll
  for (int ni = 0; ni < 4; ni++)
#pragma unroll
    for (int r = 0; r < 4; r++)
      Cred[(wv * 16 + quad * 4 + r) * 67 + ni * 16 + m16] = acc4[ni][r];
  __syncthreads();
  {
    int o = tid >> 2;                // 0..63
    int qg = (tid & 3) * 4;          // 0,4,8,12
    float4v s;
#pragma unroll
    for (int j = 0; j < 4; j++)
      s[j] = Cred[(0 * 16 + qg + j) * 67 + o] + Cred[(1 * 16 + qg + j) * 67 + o] +
             Cred[(2 * 16 + qg + j) * 67 + o] + Cred[(3 * 16 + qg + j) * 67 + o];
    size_t oid = ((size_t)(n * 64 + o)) * 9216 + q0 + qg;
    float4v r4 = *(const float4v*)&inl[oid];
    float4v y;
#pragma unroll
    for (int j = 0; j < 4; j++) y[j] = 0.25f * s[j] + r4[j];
    *(float4v*)&out[oid] = y;
  }
}

extern "C" void kernel_launch(void* const* d_in, const int* in_sizes, int n_in,
                              void* d_out, int out_size, void* d_ws, size_t ws_size,
                              hipStream_t stream)
{
  (void)in_sizes; (void)n_in; (void)out_size;
  const float* input_l = (const float*)d_in[0];
  const float* input_s = (const float*)d_in[1];
  const float* w_mlb = (const float*)d_in[2];
  const float* b_mlb = (const float*)d_in[3];
  const float* a_mlb = (const float*)d_in[4];
  const float* w_m   = (const float*)d_in[5];
  const float* b_m   = (const float*)d_in[6];
  const float* a_m   = (const float*)d_in[7];
  const float* w_asm = (const float*)d_in[8];
  const float* b_asm = (const float*)d_in[9];
  const float* a_asm = (const float*)d_in[10];
  float* out = (float*)d_out;

  char* base = (char*)d_ws;
  size_t off = 0;
  auto carve = [&](size_t bytes) -> char* {
    char* r = base + off;
    off += (bytes + 255) & ~(size_t)255;
    return r;
  };

  float* MBpad   = (float*)carve((size_t)4 * 32 * 98 * 98 * 4);
  float* REFpad  = (float*)carve((size_t)4 * 32 * 50 * 50 * 4);
  float* BASEpad = (float*)carve((size_t)4 * 64 * 50 * 50 * 4);
  bf16*  Kp      = (bf16*)carve((size_t)4 * 2304 * 320 * 2);
  bf16*  Xp      = (bf16*)carve((size_t)4 * 9216 * 320 * 2);
  bf16*  Bb      = (bf16*)carve((size_t)4 * 64 * 2304 * 2);
  float* statsM  = (float*)carve((size_t)9 * 9216 * 4);
  float* statsZ  = (float*)carve((size_t)9 * 9216 * 4);
  float* alpha   = (float*)carve((size_t)9 * 9216 * 4);
  size_t fixedOff = off;

  auto need = [&](int qmax) -> size_t {
    return fixedOff + (((size_t)qmax * 2304 * 2 + 255) & ~(size_t)255);
  };
  int nsplit, qmax, psplit;
  if (need(9216) <= ws_size)      { nsplit = 1; qmax = 9216; psplit = 9216; }
  else if (need(5120) <= ws_size) { nsplit = 2; qmax = 5120; psplit = 4608; }
  else                            { nsplit = 4; qmax = 2816; psplit = 2304; }

  bf16* attnT = (bf16*)carve((size_t)qmax * 2304 * 2);

  // ---- prep (all samples, 2 dispatches) ----
  {
    int t1 = 4 * 32 * 98 * 98;
    int t2 = 4 * 32 * 50 * 50;
    int t3 = 4 * 64 * 50 * 50;
    int tt = t1 + t2 + t3;
    k_conv_all<<<dim3((tt + 255) / 256), dim3(256), 0, stream>>>(
        input_l, input_s, w_mlb, b_mlb, a_mlb, w_m, b_m, a_m, w_asm, b_asm, a_asm,
        MBpad, REFpad, BASEpad, t1, t2, t3);
    k_gather_all<<<dim3(2304 + 46080 + 2304), dim3(256), 0, stream>>>(
        MBpad, REFpad, BASEpad, Kp, Xp, Bb);
  }

  // ---- attention per (sample, query band) ----
  for (int n = 0; n < 4; n++) {
    for (int s = 0; s < nsplit; s++) {
      int q0 = s * psplit;
      int qlo = q0 - 256; if (qlo < 0) qlo = 0;
      int qhi = q0 + psplit + 256; if (qhi > 9216) qhi = 9216;
      int qlen = qhi - qlo;  // multiple of 256 by construction
      k_qk<<<dim3(qlen / 64, 9), dim3(256), 0, stream>>>(Xp, Kp, attnT, statsM, statsZ, n, qlo);
      k_alpha<<<dim3(qlen / 256), dim3(256), 0, stream>>>(statsM, statsZ, alpha, qlo, qlen);
      k_pv4<<<dim3(psplit / 16), dim3(256), 0, stream>>>(attnT, alpha, Bb, input_l, out, n, q0, qlo);
    }
  }
}